// Round 1
// baseline (256.176 us; speedup 1.0000x reference)
//
#include <hip/hip_runtime.h>
#include <math.h>

#define NEG_SLOPE 0.1f

__device__ __forceinline__ float lrelu(float x) { return x >= 0.0f ? x : NEG_SLOPE * x; }

// ---------------------------------------------------------------------------
// Kernel 1: per-batch vector chain.
//   dvec = mean(deg, HW)            [B,512]
//   kern = lrelu(dvec@Ws^T @ Wk1^T) @ Wk2^T  -> [B,576]  (dynamic 3x3 dw kernels)
//   att  = sigmoid(lrelu(dvec@Wac^T @ Wdu1^T) @ Wdu2^T) -> [B,64]
// One block per batch, 256 threads (4 waves).
// ---------------------------------------------------------------------------
__global__ __launch_bounds__(256) void prep_kernel(
    const float* __restrict__ deg, const float* __restrict__ W_size,
    const float* __restrict__ W_k1, const float* __restrict__ W_k2,
    const float* __restrict__ W_ac, const float* __restrict__ W_du1,
    const float* __restrict__ W_du2, float* __restrict__ kern_ws,
    float* __restrict__ att_ws) {
  const int b = blockIdx.x;
  const int t = threadIdx.x;
  const int wave = t >> 6, lane = t & 63;
  __shared__ float dvec[512];
  __shared__ float fbuf[64], fabuf[64];
  __shared__ float t1[8], t2[8];

  const float* degb = deg + (size_t)b * 512 * 64;
  // wave-per-row mean over 8x8=64 elements (coalesced 64-lane load + shuffle reduce)
  for (int d = wave; d < 512; d += 4) {
    float v = degb[d * 64 + lane];
    #pragma unroll
    for (int s = 32; s > 0; s >>= 1) v += __shfl_xor(v, s, 64);
    if (lane == 0) dvec[d] = v * (1.0f / 64.0f);
  }
  __syncthreads();

  // f = dvec @ W_size^T ; fa = dvec @ W_ac^T   (wave per output channel)
  for (int c = wave; c < 64; c += 4) {
    float p1 = 0.0f, p2 = 0.0f;
    for (int j = lane; j < 512; j += 64) {
      float dv = dvec[j];
      p1 += dv * W_size[c * 512 + j];
      p2 += dv * W_ac[c * 512 + j];
    }
    #pragma unroll
    for (int s = 32; s > 0; s >>= 1) {
      p1 += __shfl_xor(p1, s, 64);
      p2 += __shfl_xor(p2, s, 64);
    }
    if (lane == 0) { fbuf[c] = p1; fabuf[c] = p2; }
  }
  __syncthreads();

  // t1 = lrelu(f @ Wk1^T) [8] ; t2 = lrelu(fa @ Wdu1^T) [8]
  if (t < 8) {
    float s1 = 0.0f, s2 = 0.0f;
    for (int c = 0; c < 64; ++c) {
      s1 += fbuf[c] * W_k1[t * 64 + c];
      s2 += fabuf[c] * W_du1[t * 64 + c];
    }
    t1[t] = lrelu(s1);
    t2[t] = lrelu(s2);
  }
  __syncthreads();

  // kern = t1 @ Wk2^T [576]
  for (int i = t; i < 576; i += 256) {
    float s = 0.0f;
    #pragma unroll
    for (int r = 0; r < 8; ++r) s += t1[r] * W_k2[i * 8 + r];
    kern_ws[b * 576 + i] = s;
  }
  // att = sigmoid(t2 @ Wdu2^T) [64]
  if (t < 64) {
    float s = 0.0f;
    #pragma unroll
    for (int r = 0; r < 8; ++r) s += t2[r] * W_du2[t * 8 + r];
    att_ws[b * 64 + t] = 1.0f / (1.0f + expf(-s));
  }
}

// ---------------------------------------------------------------------------
// Kernel 2: fused depthwise-3x3 + lrelu + 1x1 conv + bias + att*feat residual.
// Grid (H=128, B=16), 256 threads. One block = one (b, h) output row,
// all 64 channels.
//   Phase 1: z[c][w] = lrelu(dwconv3x3(feat)[b,c,h,w]) -> LDS (64x128 fp32)
//   Phase 2: out[o][w] = sum_c Wc[o][c]*z[c][w] + b[o] + att[o]*feat[o][w]
//            register tile 8 o x 4 w per thread, LDS micro-GEMM.
// ---------------------------------------------------------------------------
__global__ __launch_bounds__(256) void fused_kernel(
    const float* __restrict__ feat, const float* __restrict__ W_conv,
    const float* __restrict__ b_conv, const float* __restrict__ kern_ws,
    const float* __restrict__ att_ws, float* __restrict__ out) {
  const int h = blockIdx.x;
  const int b = blockIdx.y;
  const int t = threadIdx.x;

  __shared__ __align__(16) float zs[64 * 128];  // z tile (c-major rows of 128)
  __shared__ __align__(16) float wt[64 * 64];   // wt[c][o] = W_conv[o][c]
  __shared__ float ks[576];
  __shared__ float atts[64];
  __shared__ float bcs[64];

  // Stage W_conv transposed (so phase-2 o-reads are contiguous float4).
  for (int i = t; i < 4096; i += 256) {
    int c = i >> 6, o = i & 63;
    wt[i] = W_conv[o * 64 + c];
  }
  for (int i = t; i < 576; i += 256) ks[i] = kern_ws[b * 576 + i];
  if (t < 64) { atts[t] = att_ws[b * 64 + t]; bcs[t] = b_conv[t]; }
  __syncthreads();

  const int wg = t & 31;        // 32 w-groups of 4 pixels
  const int w0 = wg * 4;
  const int cg = t >> 5;        // 8 channel groups
  const size_t base_b = (size_t)b * 64 * 128 * 128;

  // ---- Phase 1: depthwise 3x3 + lrelu for row h, channels cg, cg+8, ... ----
  for (int c = cg; c < 64; c += 8) {
    const float* kc = &ks[c * 9];
    const float k0 = kc[0], k1 = kc[1], k2 = kc[2];
    const float k3 = kc[3], k4 = kc[4], k5 = kc[5];
    const float k6 = kc[6], k7 = kc[7], k8 = kc[8];
    float a0 = 0.0f, a1 = 0.0f, a2 = 0.0f, a3 = 0.0f;
    const float* fc = feat + base_b + (size_t)c * 16384;

    auto row_acc = [&](const float* rowp, float ka, float kb, float kcv) {
      float4 m = *(const float4*)(rowp + w0);
      float left  = (w0 > 0)   ? rowp[w0 - 1] : 0.0f;
      float right = (w0 < 124) ? rowp[w0 + 4] : 0.0f;
      a0 += ka * left + kb * m.x + kcv * m.y;
      a1 += ka * m.x  + kb * m.y + kcv * m.z;
      a2 += ka * m.y  + kb * m.z + kcv * m.w;
      a3 += ka * m.z  + kb * m.w + kcv * right;
    };
    if (h > 0)   row_acc(fc + (size_t)(h - 1) * 128, k0, k1, k2);
                 row_acc(fc + (size_t)h * 128,       k3, k4, k5);
    if (h < 127) row_acc(fc + (size_t)(h + 1) * 128, k6, k7, k8);

    float4 zv;
    zv.x = lrelu(a0); zv.y = lrelu(a1); zv.z = lrelu(a2); zv.w = lrelu(a3);
    *(float4*)&zs[c * 128 + w0] = zv;
  }
  __syncthreads();

  // ---- Phase 2: 1x1 conv micro-GEMM + residual epilogue ----
  const int og = t >> 5;        // 8 o-groups of 8 outputs
  const int o0 = og * 8;

  float acc[8][4];
  #pragma unroll
  for (int i = 0; i < 8; ++i)
    #pragma unroll
    for (int j = 0; j < 4; ++j) acc[i][j] = 0.0f;

  #pragma unroll 8
  for (int c = 0; c < 64; ++c) {
    float4 zv = *(const float4*)&zs[c * 128 + w0];
    float4 wa = *(const float4*)&wt[c * 64 + o0];
    float4 wb = *(const float4*)&wt[c * 64 + o0 + 4];
    float wv[8] = {wa.x, wa.y, wa.z, wa.w, wb.x, wb.y, wb.z, wb.w};
    float zz[4] = {zv.x, zv.y, zv.z, zv.w};
    #pragma unroll
    for (int i = 0; i < 8; ++i)
      #pragma unroll
      for (int j = 0; j < 4; ++j) acc[i][j] += wv[i] * zz[j];
  }

  #pragma unroll
  for (int i = 0; i < 8; ++i) {
    const int o = o0 + i;
    const size_t off = base_b + (size_t)o * 16384 + (size_t)h * 128 + (size_t)w0;
    float4 fv = *(const float4*)(feat + off);
    const float at = atts[o], bo = bcs[o];
    float4 ov;
    ov.x = acc[i][0] + bo + at * fv.x;
    ov.y = acc[i][1] + bo + at * fv.y;
    ov.z = acc[i][2] + bo + at * fv.z;
    ov.w = acc[i][3] + bo + at * fv.w;
    *(float4*)(out + off) = ov;
  }
}

extern "C" void kernel_launch(void* const* d_in, const int* in_sizes, int n_in,
                              void* d_out, int out_size, void* d_ws, size_t ws_size,
                              hipStream_t stream) {
  const float* feat   = (const float*)d_in[0];
  const float* deg    = (const float*)d_in[1];
  const float* W_size = (const float*)d_in[2];
  const float* W_k1   = (const float*)d_in[3];
  const float* W_k2   = (const float*)d_in[4];
  const float* W_conv = (const float*)d_in[5];
  const float* b_conv = (const float*)d_in[6];
  const float* W_ac   = (const float*)d_in[7];
  const float* W_du1  = (const float*)d_in[8];
  const float* W_du2  = (const float*)d_in[9];
  float* out = (float*)d_out;

  float* kern_ws = (float*)d_ws;            // 16*576 floats
  float* att_ws  = kern_ws + 16 * 576;      // 16*64 floats

  prep_kernel<<<16, 256, 0, stream>>>(deg, W_size, W_k1, W_k2, W_ac, W_du1,
                                      W_du2, kern_ws, att_ws);
  fused_kernel<<<dim3(128, 16), 256, 0, stream>>>(feat, W_conv, b_conv,
                                                  kern_ws, att_ws, out);
}

// Round 2
// 183.624 us; speedup vs baseline: 1.3951x; 1.3951x over previous
//
#include <hip/hip_runtime.h>
#include <math.h>

#define NEG_SLOPE 0.1f

typedef __attribute__((ext_vector_type(8))) short short8;
typedef __attribute__((ext_vector_type(4))) float floatx4;

__device__ __forceinline__ float lrelu(float x) { return x >= 0.0f ? x : NEG_SLOPE * x; }

// fp32 -> bf16 round-to-nearest-even
__device__ __forceinline__ unsigned short f2bf(float x) {
  unsigned u = __float_as_uint(x);
  return (unsigned short)((u + 0x7fffu + ((u >> 16) & 1u)) >> 16);
}

__device__ __forceinline__ float wave_sum64(float v) {
  #pragma unroll
  for (int s = 32; s > 0; s >>= 1) v += __shfl_xor(v, s, 64);
  return v;
}

// ---------------------------------------------------------------------------
// Kernel 1: per-batch vector chain (ILP-restructured).
// One block per batch, 256 threads.
// ---------------------------------------------------------------------------
__global__ __launch_bounds__(256) void prep_kernel(
    const float* __restrict__ deg, const float* __restrict__ W_size,
    const float* __restrict__ W_k1, const float* __restrict__ W_k2,
    const float* __restrict__ W_ac, const float* __restrict__ W_du1,
    const float* __restrict__ W_du2, float* __restrict__ kern_ws,
    float* __restrict__ att_ws) {
  const int b = blockIdx.x;
  const int t = threadIdx.x;
  __shared__ float dvec[512];
  __shared__ float fbuf[64], fabuf[64];
  __shared__ float t1s[8], t2s[8];

  const float* degb = deg + (size_t)b * 32768;
  const int q = t & 3, r0 = t >> 2;

  // ---- dvec = mean(deg, HW): 8 rows/thread, 4 threads/row, 32 indep float4 loads
  float rs[8];
  #pragma unroll
  for (int u = 0; u < 8; ++u) {
    const float* rp = degb + (size_t)(r0 + u * 64) * 64 + q * 16;
    float4 x0 = *(const float4*)(rp);
    float4 x1 = *(const float4*)(rp + 4);
    float4 x2 = *(const float4*)(rp + 8);
    float4 x3 = *(const float4*)(rp + 12);
    rs[u] = (x0.x + x0.y + x0.z + x0.w) + (x1.x + x1.y + x1.z + x1.w) +
            (x2.x + x2.y + x2.z + x2.w) + (x3.x + x3.y + x3.z + x3.w);
  }
  #pragma unroll
  for (int u = 0; u < 8; ++u) {
    float s = rs[u];
    s += __shfl_xor(s, 1, 64);
    s += __shfl_xor(s, 2, 64);
    if (q == 0) dvec[r0 + u * 64] = s * (1.0f / 64.0f);
  }
  __syncthreads();

  // ---- f = dvec @ W_size^T ; fa = dvec @ W_ac^T  (4 threads per channel, float4)
  {
    const int c = t >> 2;
    const float* ws = W_size + (size_t)c * 512;
    const float* wa = W_ac + (size_t)c * 512;
    float p1 = 0.0f, p2 = 0.0f;
    #pragma unroll 4
    for (int k = 0; k < 32; ++k) {
      const int e = q * 4 + k * 16;
      float4 d  = *(const float4*)&dvec[e];
      float4 w1 = *(const float4*)(ws + e);
      float4 w2 = *(const float4*)(wa + e);
      p1 += d.x * w1.x + d.y * w1.y + d.z * w1.z + d.w * w1.w;
      p2 += d.x * w2.x + d.y * w2.y + d.z * w2.z + d.w * w2.w;
    }
    p1 += __shfl_xor(p1, 1, 64); p1 += __shfl_xor(p1, 2, 64);
    p2 += __shfl_xor(p2, 1, 64); p2 += __shfl_xor(p2, 2, 64);
    if (q == 0) { fbuf[c] = p1; fabuf[c] = p2; }
  }
  __syncthreads();

  // ---- t1 = lrelu(f @ Wk1^T) [8]; t2 = lrelu(fa @ Wdu1^T) [8]  (wave 0 / wave 1)
  const int wave = t >> 6, lane = t & 63;
  if (wave == 0) {
    float v = fbuf[lane];
    #pragma unroll
    for (int rr = 0; rr < 8; ++rr) {
      float p = wave_sum64(v * W_k1[rr * 64 + lane]);
      if (lane == 0) t1s[rr] = lrelu(p);
    }
  } else if (wave == 1) {
    float v = fabuf[lane];
    #pragma unroll
    for (int rr = 0; rr < 8; ++rr) {
      float p = wave_sum64(v * W_du1[rr * 64 + lane]);
      if (lane == 0) t2s[rr] = lrelu(p);
    }
  }
  __syncthreads();

  // ---- kern = t1 @ Wk2^T [576]
  for (int i = t; i < 576; i += 256) {
    float4 wa0 = *(const float4*)&W_k2[i * 8];
    float4 wa1 = *(const float4*)&W_k2[i * 8 + 4];
    float s = t1s[0] * wa0.x + t1s[1] * wa0.y + t1s[2] * wa0.z + t1s[3] * wa0.w +
              t1s[4] * wa1.x + t1s[5] * wa1.y + t1s[6] * wa1.z + t1s[7] * wa1.w;
    kern_ws[b * 576 + i] = s;
  }
  // ---- att = sigmoid(t2 @ Wdu2^T) [64]
  if (t < 64) {
    float4 wa0 = *(const float4*)&W_du2[t * 8];
    float4 wa1 = *(const float4*)&W_du2[t * 8 + 4];
    float s = t2s[0] * wa0.x + t2s[1] * wa0.y + t2s[2] * wa0.z + t2s[3] * wa0.w +
              t2s[4] * wa1.x + t2s[5] * wa1.y + t2s[6] * wa1.z + t2s[7] * wa1.w;
    att_ws[b * 64 + t] = 1.0f / (1.0f + expf(-s));
  }
}

// ---------------------------------------------------------------------------
// Kernel 2: fused dw3x3+lrelu (fp32 VALU) + 1x1 conv (bf16 MFMA) + epilogue.
// One block per (b, h) row. 256 threads = 4 waves.
//   LDS zT[w][c] bf16, row stride 72 shorts, chunk-XOR-swizzled.
//   LDS wt[o][c] bf16, same layout.
//   Phase 2: D[64 o x 128 w] = W @ z via mfma_f32_16x16x32_bf16:
//     wave m-tile (16 o), 8 n-tiles (16 w), 2 k-steps (32 c).
// ---------------------------------------------------------------------------
__global__ __launch_bounds__(256, 4) void fused_kernel(
    const float* __restrict__ feat, const float* __restrict__ W_conv,
    const float* __restrict__ b_conv, const float* __restrict__ kern_ws,
    const float* __restrict__ att_ws, float* __restrict__ out) {
  // XCD-aware swizzle: each XCD (round-robin on linear block id % 8) owns a
  // contiguous 16-row h-stripe -> halo rows reused in that XCD's L2.
  const int L = blockIdx.y * 128 + blockIdx.x;
  const int xcd = L & 7;
  const int rr_ = L >> 3;
  const int h = xcd * 16 + (rr_ & 15);
  const int b = rr_ >> 4;

  const int t = threadIdx.x;

  __shared__ __align__(16) unsigned short zT[128 * 72];  // zT[w*72 + swz(c)]
  __shared__ __align__(16) unsigned short wt[64 * 72];   // wt[o*72 + swz(c)]
  __shared__ float ks[576];
  __shared__ float atts[64];
  __shared__ float bcs[64];

  // ---- stage wt (bf16, swizzled) + ks + atts + bcs ----
  {
    const int o = t >> 2;
    const int c0 = (t & 3) * 16;
    const float* wp = W_conv + o * 64 + c0;
    float4 a0 = *(const float4*)(wp);
    float4 a1 = *(const float4*)(wp + 4);
    float4 a2 = *(const float4*)(wp + 8);
    float4 a3 = *(const float4*)(wp + 12);
    const int sw = (o >> 2) & 7;
    short8 p0, p1;
    p0[0] = f2bf(a0.x); p0[1] = f2bf(a0.y); p0[2] = f2bf(a0.z); p0[3] = f2bf(a0.w);
    p0[4] = f2bf(a1.x); p0[5] = f2bf(a1.y); p0[6] = f2bf(a1.z); p0[7] = f2bf(a1.w);
    p1[0] = f2bf(a2.x); p1[1] = f2bf(a2.y); p1[2] = f2bf(a2.z); p1[3] = f2bf(a2.w);
    p1[4] = f2bf(a3.x); p1[5] = f2bf(a3.y); p1[6] = f2bf(a3.z); p1[7] = f2bf(a3.w);
    const int kc0 = (c0 >> 3) ^ sw;
    const int kc1 = ((c0 >> 3) + 1) ^ sw;
    *(short8*)&wt[o * 72 + kc0 * 8] = p0;
    *(short8*)&wt[o * 72 + kc1 * 8] = p1;
  }
  for (int i = t; i < 576; i += 256) ks[i] = kern_ws[b * 576 + i];
  if (t < 64) { atts[t] = att_ws[b * 64 + t]; bcs[t] = b_conv[t]; }
  __syncthreads();

  const size_t base_b = (size_t)b * 64 * 128 * 128;

  // ---- Phase 1: depthwise 3x3 + lrelu -> zT (bf16) ----
  {
    const int c8 = t & 7;          // channel low bits
    const int gg = t >> 3;         // 0..31 -> w0 = gg*4
    const int w0 = gg * 4;
    const int swz = gg & 7;        // (w>>2)&7, same for w0..w0+3

    #pragma unroll
    for (int it = 0; it < 8; ++it) {
      const int c = c8 + 8 * it;
      const float* kc = &ks[c * 9];
      const float k0 = kc[0], k1 = kc[1], k2 = kc[2];
      const float k3 = kc[3], k4 = kc[4], k5 = kc[5];
      const float k6 = kc[6], k7 = kc[7], k8 = kc[8];
      float a0 = 0.0f, a1 = 0.0f, a2 = 0.0f, a3 = 0.0f;
      const float* fc = feat + base_b + (size_t)c * 16384;

      auto row_acc = [&](const float* rowp, float ka, float kb, float kcv) {
        float4 m = *(const float4*)(rowp + w0);
        float left  = (w0 > 0)   ? rowp[w0 - 1] : 0.0f;
        float right = (w0 < 124) ? rowp[w0 + 4] : 0.0f;
        a0 += ka * left + kb * m.x + kcv * m.y;
        a1 += ka * m.x  + kb * m.y + kcv * m.z;
        a2 += ka * m.y  + kb * m.z + kcv * m.w;
        a3 += ka * m.z  + kb * m.w + kcv * right;
      };
      if (h > 0)   row_acc(fc + (size_t)(h - 1) * 128, k0, k1, k2);
                   row_acc(fc + (size_t)h * 128,       k3, k4, k5);
      if (h < 127) row_acc(fc + (size_t)(h + 1) * 128, k6, k7, k8);

      const int cbase = ((it ^ swz) * 8) + c8;  // swizzled chunk + in-chunk offset
      zT[(w0 + 0) * 72 + cbase] = f2bf(lrelu(a0));
      zT[(w0 + 1) * 72 + cbase] = f2bf(lrelu(a1));
      zT[(w0 + 2) * 72 + cbase] = f2bf(lrelu(a2));
      zT[(w0 + 3) * 72 + cbase] = f2bf(lrelu(a3));
    }
  }
  __syncthreads();

  // ---- Phase 2: 1x1 conv via MFMA ----
  {
    const int lane = t & 63, wave = t >> 6;
    const int r = lane & 15, q = lane >> 4;
    const int m0 = wave * 16;

    short8 afrag[2];
    #pragma unroll
    for (int ksp = 0; ksp < 2; ++ksp) {
      const int o = m0 + r;
      const int kc = (ksp * 4 + q) ^ ((o >> 2) & 7);
      afrag[ksp] = *(const short8*)&wt[o * 72 + kc * 8];
    }

    floatx4 acc[8];
    #pragma unroll
    for (int nt = 0; nt < 8; ++nt) acc[nt] = (floatx4){0.f, 0.f, 0.f, 0.f};

    #pragma unroll
    for (int nt = 0; nt < 8; ++nt) {
      const int w = nt * 16 + r;
      const int sw = (w >> 2) & 7;
      #pragma unroll
      for (int ksp = 0; ksp < 2; ++ksp) {
        const int kc = (ksp * 4 + q) ^ sw;
        short8 bfrag = *(const short8*)&zT[w * 72 + kc * 8];
        acc[nt] = __builtin_amdgcn_mfma_f32_16x16x32_bf16(afrag[ksp], bfrag,
                                                          acc[nt], 0, 0, 0);
      }
    }

    // ---- epilogue: + bias + att*feat, scalar stores (64B segments/wave) ----
    #pragma unroll
    for (int nt = 0; nt < 8; ++nt) {
      const int w = nt * 16 + r;
      #pragma unroll
      for (int reg = 0; reg < 4; ++reg) {
        const int o = m0 + q * 4 + reg;
        const size_t idx = base_b + (size_t)o * 16384 + (size_t)h * 128 + w;
        out[idx] = acc[nt][reg] + bcs[o] + atts[o] * feat[idx];
      }
    }
  }
}

extern "C" void kernel_launch(void* const* d_in, const int* in_sizes, int n_in,
                              void* d_out, int out_size, void* d_ws, size_t ws_size,
                              hipStream_t stream) {
  const float* feat   = (const float*)d_in[0];
  const float* deg    = (const float*)d_in[1];
  const float* W_size = (const float*)d_in[2];
  const float* W_k1   = (const float*)d_in[3];
  const float* W_k2   = (const float*)d_in[4];
  const float* W_conv = (const float*)d_in[5];
  const float* b_conv = (const float*)d_in[6];
  const float* W_ac   = (const float*)d_in[7];
  const float* W_du1  = (const float*)d_in[8];
  const float* W_du2  = (const float*)d_in[9];
  float* out = (float*)d_out;

  float* kern_ws = (float*)d_ws;            // 16*576 floats
  float* att_ws  = kern_ws + 16 * 576;      // 16*64 floats

  prep_kernel<<<16, 256, 0, stream>>>(deg, W_size, W_k1, W_k2, W_ac, W_du1,
                                      W_du2, kern_ws, att_ws);
  fused_kernel<<<dim3(128, 16), 256, 0, stream>>>(feat, W_conv, b_conv,
                                                  kern_ws, att_ws, out);
}

// Round 3
// 183.009 us; speedup vs baseline: 1.3998x; 1.0034x over previous
//
#include <hip/hip_runtime.h>
#include <math.h>

#define NEG_SLOPE 0.1f

typedef __attribute__((ext_vector_type(8))) short short8;
typedef __attribute__((ext_vector_type(4))) short short4v;
typedef __attribute__((ext_vector_type(4))) float floatx4;

__device__ __forceinline__ float lrelu(float x) { return x >= 0.0f ? x : NEG_SLOPE * x; }

// fp32 -> bf16 round-to-nearest-even
__device__ __forceinline__ unsigned short f2bf(float x) {
  unsigned u = __float_as_uint(x);
  return (unsigned short)((u + 0x7fffu + ((u >> 16) & 1u)) >> 16);
}

__device__ __forceinline__ float wave_sum64(float v) {
  #pragma unroll
  for (int s = 32; s > 0; s >>= 1) v += __shfl_xor(v, s, 64);
  return v;
}

// ---------------------------------------------------------------------------
// prep1: dvec = mean(deg, HW)  [16,512]. Grid 64 blocks x 256 thr.
// block k: b = k>>2, 128 d-rows. 2 threads/row, 8 indep float4 each.
// ---------------------------------------------------------------------------
__global__ __launch_bounds__(256) void prep1_kernel(
    const float* __restrict__ deg, float* __restrict__ dvec_ws) {
  const int k = blockIdx.x;
  const int b = k >> 2, quar = k & 3;
  const int t = threadIdx.x;
  const int rw = t >> 1, half = t & 1;
  const int d = quar * 128 + rw;
  const float* p = deg + (size_t)b * 32768 + (size_t)d * 64 + half * 32;
  float4 x0 = *(const float4*)(p);
  float4 x1 = *(const float4*)(p + 4);
  float4 x2 = *(const float4*)(p + 8);
  float4 x3 = *(const float4*)(p + 12);
  float4 x4 = *(const float4*)(p + 16);
  float4 x5 = *(const float4*)(p + 20);
  float4 x6 = *(const float4*)(p + 24);
  float4 x7 = *(const float4*)(p + 28);
  float s = (x0.x + x0.y + x0.z + x0.w) + (x1.x + x1.y + x1.z + x1.w) +
            (x2.x + x2.y + x2.z + x2.w) + (x3.x + x3.y + x3.z + x3.w) +
            (x4.x + x4.y + x4.z + x4.w) + (x5.x + x5.y + x5.z + x5.w) +
            (x6.x + x6.y + x6.z + x6.w) + (x7.x + x7.y + x7.z + x7.w);
  s += __shfl_xor(s, 1, 64);
  if (half == 0) dvec_ws[b * 512 + d] = s * (1.0f / 64.0f);
}

// ---------------------------------------------------------------------------
// prep2: f = dvec@W_size^T, fa = dvec@W_ac^T  [16,64]. Grid 64 x 256.
// block k: b = k>>2, 16 channels; 16 threads/channel.
// ---------------------------------------------------------------------------
__global__ __launch_bounds__(256) void prep2_kernel(
    const float* __restrict__ dvec_ws, const float* __restrict__ W_size,
    const float* __restrict__ W_ac, float* __restrict__ f_ws,
    float* __restrict__ fa_ws) {
  const int k = blockIdx.x;
  const int b = k >> 2, cq = k & 3;
  const int t = threadIdx.x;
  const int cl = t >> 4, sub = t & 15;
  const int c = cq * 16 + cl;
  const float* dv = dvec_ws + b * 512;
  const float* w1 = W_size + (size_t)c * 512;
  const float* w2 = W_ac + (size_t)c * 512;
  float p1 = 0.0f, p2 = 0.0f;
  #pragma unroll
  for (int kk = 0; kk < 8; ++kk) {
    const int e = sub * 4 + kk * 64;
    float4 d  = *(const float4*)(dv + e);
    float4 a  = *(const float4*)(w1 + e);
    float4 bq = *(const float4*)(w2 + e);
    p1 += d.x * a.x + d.y * a.y + d.z * a.z + d.w * a.w;
    p2 += d.x * bq.x + d.y * bq.y + d.z * bq.z + d.w * bq.w;
  }
  #pragma unroll
  for (int s = 1; s < 16; s <<= 1) {
    p1 += __shfl_xor(p1, s, 64);
    p2 += __shfl_xor(p2, s, 64);
  }
  if (sub == 0) { f_ws[b * 64 + c] = p1; fa_ws[b * 64 + c] = p2; }
}

// ---------------------------------------------------------------------------
// prep3: t1/t2 (8-dim), kern [16,576], att [16,64]. Grid 16 x 256.
// ---------------------------------------------------------------------------
__global__ __launch_bounds__(256) void prep3_kernel(
    const float* __restrict__ f_ws, const float* __restrict__ fa_ws,
    const float* __restrict__ W_k1, const float* __restrict__ W_k2,
    const float* __restrict__ W_du1, const float* __restrict__ W_du2,
    float* __restrict__ kern_ws, float* __restrict__ att_ws) {
  const int b = blockIdx.x;
  const int t = threadIdx.x;
  __shared__ float t1s[8], t2s[8];
  const int wave = t >> 6, lane = t & 63;
  if (wave == 0) {
    float v = f_ws[b * 64 + lane];
    #pragma unroll
    for (int rr = 0; rr < 8; ++rr) {
      float p = wave_sum64(v * W_k1[rr * 64 + lane]);
      if (lane == 0) t1s[rr] = lrelu(p);
    }
  } else if (wave == 1) {
    float v = fa_ws[b * 64 + lane];
    #pragma unroll
    for (int rr = 0; rr < 8; ++rr) {
      float p = wave_sum64(v * W_du1[rr * 64 + lane]);
      if (lane == 0) t2s[rr] = lrelu(p);
    }
  }
  __syncthreads();
  for (int i = t; i < 576; i += 256) {
    float4 wa0 = *(const float4*)&W_k2[i * 8];
    float4 wa1 = *(const float4*)&W_k2[i * 8 + 4];
    kern_ws[b * 576 + i] =
        t1s[0] * wa0.x + t1s[1] * wa0.y + t1s[2] * wa0.z + t1s[3] * wa0.w +
        t1s[4] * wa1.x + t1s[5] * wa1.y + t1s[6] * wa1.z + t1s[7] * wa1.w;
  }
  if (t < 64) {
    float4 wa0 = *(const float4*)&W_du2[t * 8];
    float4 wa1 = *(const float4*)&W_du2[t * 8 + 4];
    float s = t2s[0] * wa0.x + t2s[1] * wa0.y + t2s[2] * wa0.z + t2s[3] * wa0.w +
              t2s[4] * wa1.x + t2s[5] * wa1.y + t2s[6] * wa1.z + t2s[7] * wa1.w;
    att_ws[b * 64 + t] = 1.0f / (1.0f + expf(-s));
  }
}

// ---------------------------------------------------------------------------
// fused: dw3x3+lrelu (fp32) + 1x1 conv (bf16 MFMA, operand-swapped) + epilogue.
// Grid 1024 x 256 thr; each block does 2 consecutive h rows of one b.
//   bid -> xcd = bid&7 owns h-stripe [16*xcd, 16*xcd+16) (L2 halo locality).
// LDS: zT[w][c] bf16 stride 72, XOR-swizzled chunks; wt[o][c] same.
// Phase 2: D[w][o]: A = z (m=w), B = wt (n=o) -> lane acc is w-contiguous
//   => float4 epilogue loads/stores.
// ---------------------------------------------------------------------------
__global__ __launch_bounds__(256, 4) void fused_kernel(
    const float* __restrict__ feat, const float* __restrict__ W_conv,
    const float* __restrict__ b_conv, const float* __restrict__ kern_ws,
    const float* __restrict__ att_ws, float* __restrict__ out) {
  const int bid = blockIdx.x;
  const int xcd = bid & 7;
  const int idx = bid >> 3;
  const int b = idx >> 3;
  const int sub = idx & 7;
  const int h_base = xcd * 16 + sub * 2;

  const int t = threadIdx.x;

  __shared__ __align__(16) unsigned short zT[128 * 72];
  __shared__ __align__(16) unsigned short wt[64 * 72];
  __shared__ float ks[576];
  __shared__ float atts[64];
  __shared__ float bcs[64];

  // ---- stage wt (bf16, swizzled), ks, atts, bcs (once per block) ----
  {
    const int o = t >> 2;
    const int c0 = (t & 3) * 16;
    const float* wp = W_conv + o * 64 + c0;
    float4 a0 = *(const float4*)(wp);
    float4 a1 = *(const float4*)(wp + 4);
    float4 a2 = *(const float4*)(wp + 8);
    float4 a3 = *(const float4*)(wp + 12);
    const int sw = ((o >> 2) ^ (o >> 5)) & 7;
    short8 p0, p1;
    p0[0] = f2bf(a0.x); p0[1] = f2bf(a0.y); p0[2] = f2bf(a0.z); p0[3] = f2bf(a0.w);
    p0[4] = f2bf(a1.x); p0[5] = f2bf(a1.y); p0[6] = f2bf(a1.z); p0[7] = f2bf(a1.w);
    p1[0] = f2bf(a2.x); p1[1] = f2bf(a2.y); p1[2] = f2bf(a2.z); p1[3] = f2bf(a2.w);
    p1[4] = f2bf(a3.x); p1[5] = f2bf(a3.y); p1[6] = f2bf(a3.z); p1[7] = f2bf(a3.w);
    const int kc0 = ((c0 >> 3) + 0) ^ sw;
    const int kc1 = ((c0 >> 3) + 1) ^ sw;
    *(short8*)&wt[o * 72 + kc0 * 8] = p0;
    *(short8*)&wt[o * 72 + kc1 * 8] = p1;
  }
  for (int i = t; i < 576; i += 256) ks[i] = kern_ws[b * 576 + i];
  if (t < 64) { atts[t] = att_ws[b * 64 + t]; bcs[t] = b_conv[t]; }
  __syncthreads();

  const size_t base_b = (size_t)b * 64 * 128 * 128;
  const int lane = t & 63, wave = t >> 6;
  const int cq = t >> 5;        // 0..7: channel quad group
  const int gg = t & 31;        // w-group, w0 = gg*4
  const int w0 = gg * 4;
  const int swz = (gg ^ (gg >> 3)) & 7;
  const float4 zf4 = {0.f, 0.f, 0.f, 0.f};

  #pragma unroll 1
  for (int ti = 0; ti < 2; ++ti) {
    const int h = h_base + ti;
    const bool hgt0 = (h > 0), hlt = (h < 127);
    const float* fbase = feat + base_b + (size_t)h * 128 + w0;

    // ---- Phase 1: dw3x3 + lrelu -> zT (bf16, b64 writes) ----
    #pragma unroll
    for (int it = 0; it < 2; ++it) {
      const int c0 = cq * 4 + it * 32;
      float4 top[4], mid[4], bot[4];
      #pragma unroll
      for (int j = 0; j < 4; ++j) {
        const float* p = fbase + (size_t)(c0 + j) * 16384;
        mid[j] = *(const float4*)p;
        top[j] = hgt0 ? *(const float4*)(p - 128) : zf4;
        bot[j] = hlt  ? *(const float4*)(p + 128) : zf4;
      }
      unsigned short sres[4][4];
      #pragma unroll
      for (int j = 0; j < 4; ++j) {
        const float* kv = &ks[(c0 + j) * 9];
        const float k0 = kv[0], k1 = kv[1], k2 = kv[2];
        const float k3 = kv[3], k4 = kv[4], k5 = kv[5];
        const float k6 = kv[6], k7 = kv[7], k8 = kv[8];
        float a0 = 0.f, a1 = 0.f, a2 = 0.f, a3 = 0.f;
        {
          float4 m = top[j];
          float lf = __shfl(m.w, lane - 1, 64); if (gg == 0)  lf = 0.f;
          float rt = __shfl(m.x, lane + 1, 64); if (gg == 31) rt = 0.f;
          a0 += k0 * lf  + k1 * m.x + k2 * m.y;
          a1 += k0 * m.x + k1 * m.y + k2 * m.z;
          a2 += k0 * m.y + k1 * m.z + k2 * m.w;
          a3 += k0 * m.z + k1 * m.w + k2 * rt;
        }
        {
          float4 m = mid[j];
          float lf = __shfl(m.w, lane - 1, 64); if (gg == 0)  lf = 0.f;
          float rt = __shfl(m.x, lane + 1, 64); if (gg == 31) rt = 0.f;
          a0 += k3 * lf  + k4 * m.x + k5 * m.y;
          a1 += k3 * m.x + k4 * m.y + k5 * m.z;
          a2 += k3 * m.y + k4 * m.z + k5 * m.w;
          a3 += k3 * m.z + k4 * m.w + k5 * rt;
        }
        {
          float4 m = bot[j];
          float lf = __shfl(m.w, lane - 1, 64); if (gg == 0)  lf = 0.f;
          float rt = __shfl(m.x, lane + 1, 64); if (gg == 31) rt = 0.f;
          a0 += k6 * lf  + k7 * m.x + k8 * m.y;
          a1 += k6 * m.x + k7 * m.y + k8 * m.z;
          a2 += k6 * m.y + k7 * m.z + k8 * m.w;
          a3 += k6 * m.z + k7 * m.w + k8 * rt;
        }
        sres[j][0] = f2bf(lrelu(a0));
        sres[j][1] = f2bf(lrelu(a1));
        sres[j][2] = f2bf(lrelu(a2));
        sres[j][3] = f2bf(lrelu(a3));
      }
      const int chunk = (cq >> 1) + it * 4;
      const int kcs = ((chunk ^ swz) * 8) + (cq & 1) * 4;
      #pragma unroll
      for (int i = 0; i < 4; ++i) {
        short4v sv;
        sv[0] = (short)sres[0][i]; sv[1] = (short)sres[1][i];
        sv[2] = (short)sres[2][i]; sv[3] = (short)sres[3][i];
        *(short4v*)&zT[(w0 + i) * 72 + kcs] = sv;
      }
    }
    __syncthreads();

    // ---- Phase 2: 1x1 conv via MFMA (A=z -> D rows are w) + epilogue ----
    {
      const int r = lane & 15, q = lane >> 4;

      short8 az[2][2];
      #pragma unroll
      for (int wm2 = 0; wm2 < 2; ++wm2) {
        const int w = (wave * 2 + wm2) * 16 + r;
        const int sz = ((w >> 2) ^ (w >> 5)) & 7;
        #pragma unroll
        for (int ksp = 0; ksp < 2; ++ksp) {
          const int kc = (ksp * 4 + q) ^ sz;
          az[wm2][ksp] = *(const short8*)&zT[w * 72 + kc * 8];
        }
      }
      short8 bw[4][2];
      #pragma unroll
      for (int nt = 0; nt < 4; ++nt) {
        const int o = nt * 16 + r;
        const int so = ((o >> 2) ^ (o >> 5)) & 7;
        #pragma unroll
        for (int ksp = 0; ksp < 2; ++ksp) {
          const int kc = (ksp * 4 + q) ^ so;
          bw[nt][ksp] = *(const short8*)&wt[o * 72 + kc * 8];
        }
      }

      floatx4 acc[2][4];
      #pragma unroll
      for (int wm2 = 0; wm2 < 2; ++wm2)
        #pragma unroll
        for (int nt = 0; nt < 4; ++nt) acc[wm2][nt] = (floatx4){0.f, 0.f, 0.f, 0.f};

      #pragma unroll
      for (int wm2 = 0; wm2 < 2; ++wm2)
        #pragma unroll
        for (int nt = 0; nt < 4; ++nt)
          #pragma unroll
          for (int ksp = 0; ksp < 2; ++ksp)
            acc[wm2][nt] = __builtin_amdgcn_mfma_f32_16x16x32_bf16(
                az[wm2][ksp], bw[nt][ksp], acc[wm2][nt], 0, 0, 0);

      #pragma unroll
      for (int wm2 = 0; wm2 < 2; ++wm2) {
        const int wb = (wave * 2 + wm2) * 16 + q * 4;
        #pragma unroll
        for (int nt = 0; nt < 4; ++nt) {
          const int o = nt * 16 + r;
          const size_t off = base_b + (size_t)o * 16384 + (size_t)h * 128 + wb;
          float4 fv = *(const float4*)(feat + off);
          const float at = atts[o], bo = bcs[o];
          floatx4 a = acc[wm2][nt];
          float4 ov;
          ov.x = a[0] + bo + at * fv.x;
          ov.y = a[1] + bo + at * fv.y;
          ov.z = a[2] + bo + at * fv.z;
          ov.w = a[3] + bo + at * fv.w;
          *(float4*)(out + off) = ov;
        }
      }
    }
    if (ti == 0) __syncthreads();
  }
}

extern "C" void kernel_launch(void* const* d_in, const int* in_sizes, int n_in,
                              void* d_out, int out_size, void* d_ws, size_t ws_size,
                              hipStream_t stream) {
  const float* feat   = (const float*)d_in[0];
  const float* deg    = (const float*)d_in[1];
  const float* W_size = (const float*)d_in[2];
  const float* W_k1   = (const float*)d_in[3];
  const float* W_k2   = (const float*)d_in[4];
  const float* W_conv = (const float*)d_in[5];
  const float* b_conv = (const float*)d_in[6];
  const float* W_ac   = (const float*)d_in[7];
  const float* W_du1  = (const float*)d_in[8];
  const float* W_du2  = (const float*)d_in[9];
  float* out = (float*)d_out;

  float* dvec_ws = (float*)d_ws;              // 16*512
  float* f_ws    = dvec_ws + 16 * 512;        // 16*64
  float* fa_ws   = f_ws + 16 * 64;            // 16*64
  float* kern_ws = fa_ws + 16 * 64;           // 16*576
  float* att_ws  = kern_ws + 16 * 576;        // 16*64

  prep1_kernel<<<64, 256, 0, stream>>>(deg, dvec_ws);
  prep2_kernel<<<64, 256, 0, stream>>>(dvec_ws, W_size, W_ac, f_ws, fa_ws);
  prep3_kernel<<<16, 256, 0, stream>>>(f_ws, fa_ws, W_k1, W_k2, W_du1, W_du2,
                                       kern_ws, att_ws);
  fused_kernel<<<1024, 256, 0, stream>>>(feat, W_conv, b_conv, kern_ws, att_ws,
                                         out);
}

// Round 4
// 180.737 us; speedup vs baseline: 1.4174x; 1.0126x over previous
//
#include <hip/hip_runtime.h>
#include <math.h>

#define NEG_SLOPE 0.1f

typedef __attribute__((ext_vector_type(8))) short short8;
typedef __attribute__((ext_vector_type(4))) short short4v;
typedef __attribute__((ext_vector_type(4))) float floatx4;

__device__ __forceinline__ float lrelu(float x) { return x >= 0.0f ? x : NEG_SLOPE * x; }

// fp32 -> bf16 round-to-nearest-even
__device__ __forceinline__ unsigned short f2bf(float x) {
  unsigned u = __float_as_uint(x);
  return (unsigned short)((u + 0x7fffu + ((u >> 16) & 1u)) >> 16);
}

__device__ __forceinline__ float wave_sum64(float v) {
  #pragma unroll
  for (int s = 32; s > 0; s >>= 1) v += __shfl_xor(v, s, 64);
  return v;
}

// ---------------------------------------------------------------------------
// prep: entire per-batch vector chain in ONE kernel. Grid 16 x 256 thr.
//   A: dvec = mean(deg,HW)[512]   B: f = dvec@Ws^T, fa = dvec@Wac^T [64]
//   C: t1 = lrelu(f@Wk1^T), t2 = lrelu(fa@Wdu1^T) [8]
//   D: kern = t1@Wk2^T [576], att = sigmoid(t2@Wdu2^T) [64]
// ---------------------------------------------------------------------------
__global__ __launch_bounds__(256) void prep_kernel(
    const float* __restrict__ deg, const float* __restrict__ W_size,
    const float* __restrict__ W_k1, const float* __restrict__ W_k2,
    const float* __restrict__ W_ac, const float* __restrict__ W_du1,
    const float* __restrict__ W_du2, float* __restrict__ kern_ws,
    float* __restrict__ att_ws) {
  const int b = blockIdx.x;
  const int t = threadIdx.x;
  __shared__ float dvec[512];
  __shared__ float fbuf[64], fabuf[64];
  __shared__ float t1s[8], t2s[8];

  // ---- A: dvec (2 threads/row, 8 indep float4 each, 4 rows/thread) ----
  const float* degb = deg + (size_t)b * 32768;
  const int half = t & 1, row0 = t >> 1;
  #pragma unroll
  for (int u = 0; u < 4; ++u) {
    const int d = row0 + u * 128;
    const float* p = degb + (size_t)d * 64 + half * 32;
    float4 x0 = *(const float4*)(p);
    float4 x1 = *(const float4*)(p + 4);
    float4 x2 = *(const float4*)(p + 8);
    float4 x3 = *(const float4*)(p + 12);
    float4 x4 = *(const float4*)(p + 16);
    float4 x5 = *(const float4*)(p + 20);
    float4 x6 = *(const float4*)(p + 24);
    float4 x7 = *(const float4*)(p + 28);
    float s = (x0.x + x0.y + x0.z + x0.w) + (x1.x + x1.y + x1.z + x1.w) +
              (x2.x + x2.y + x2.z + x2.w) + (x3.x + x3.y + x3.z + x3.w) +
              (x4.x + x4.y + x4.z + x4.w) + (x5.x + x5.y + x5.z + x5.w) +
              (x6.x + x6.y + x6.z + x6.w) + (x7.x + x7.y + x7.z + x7.w);
    s += __shfl_xor(s, 1, 64);
    if (half == 0) dvec[d] = s * (1.0f / 64.0f);
  }
  __syncthreads();

  // ---- B: f / fa (4 threads per channel, float4, 32 iters) ----
  {
    const int c = t >> 2, q = t & 3;
    const float* w1 = W_size + (size_t)c * 512;
    const float* w2 = W_ac + (size_t)c * 512;
    float p1 = 0.0f, p2 = 0.0f;
    #pragma unroll 4
    for (int kk = 0; kk < 32; ++kk) {
      const int e = kk * 16 + q * 4;
      float4 d4 = *(const float4*)&dvec[e];
      float4 a4 = *(const float4*)(w1 + e);
      float4 b4 = *(const float4*)(w2 + e);
      p1 += d4.x * a4.x + d4.y * a4.y + d4.z * a4.z + d4.w * a4.w;
      p2 += d4.x * b4.x + d4.y * b4.y + d4.z * b4.z + d4.w * b4.w;
    }
    p1 += __shfl_xor(p1, 1, 64); p1 += __shfl_xor(p1, 2, 64);
    p2 += __shfl_xor(p2, 1, 64); p2 += __shfl_xor(p2, 2, 64);
    if (q == 0) { fbuf[c] = p1; fabuf[c] = p2; }
  }
  __syncthreads();

  // ---- C: t1/t2 (wave 0 / wave 1) ----
  const int wave = t >> 6, lane = t & 63;
  if (wave == 0) {
    float v = fbuf[lane];
    #pragma unroll
    for (int rr = 0; rr < 8; ++rr) {
      float p = wave_sum64(v * W_k1[rr * 64 + lane]);
      if (lane == 0) t1s[rr] = lrelu(p);
    }
  } else if (wave == 1) {
    float v = fabuf[lane];
    #pragma unroll
    for (int rr = 0; rr < 8; ++rr) {
      float p = wave_sum64(v * W_du1[rr * 64 + lane]);
      if (lane == 0) t2s[rr] = lrelu(p);
    }
  }
  __syncthreads();

  // ---- D: kern [576], att [64] ----
  for (int i = t; i < 576; i += 256) {
    float4 wa0 = *(const float4*)&W_k2[i * 8];
    float4 wa1 = *(const float4*)&W_k2[i * 8 + 4];
    kern_ws[b * 576 + i] =
        t1s[0] * wa0.x + t1s[1] * wa0.y + t1s[2] * wa0.z + t1s[3] * wa0.w +
        t1s[4] * wa1.x + t1s[5] * wa1.y + t1s[6] * wa1.z + t1s[7] * wa1.w;
  }
  if (t < 64) {
    float4 wa0 = *(const float4*)&W_du2[t * 8];
    float4 wa1 = *(const float4*)&W_du2[t * 8 + 4];
    float s = t2s[0] * wa0.x + t2s[1] * wa0.y + t2s[2] * wa0.z + t2s[3] * wa0.w +
              t2s[4] * wa1.x + t2s[5] * wa1.y + t2s[6] * wa1.z + t2s[7] * wa1.w;
    att_ws[b * 64 + t] = 1.0f / (1.0f + expf(-s));
  }
}

// ---------------------------------------------------------------------------
// fused: dw3x3+lrelu (fp32) + 1x1 conv (bf16 MFMA, A=z) + epilogue.
// Grid 2048 x 256 thr; ONE (b,h) row per block.
//   b = bid>>7, h = bid&127  -> consecutive blocks share halo rows (L2/L3).
// LDS: zT[w][c] bf16 stride 72 XOR-swizzled; wt[o][c] same; ks/atts/bcs.
// ---------------------------------------------------------------------------
__global__ __launch_bounds__(256, 5) void fused_kernel(
    const float* __restrict__ feat, const float* __restrict__ W_conv,
    const float* __restrict__ b_conv, const float* __restrict__ kern_ws,
    const float* __restrict__ att_ws, float* __restrict__ out) {
  const int bid = blockIdx.x;
  const int b = bid >> 7;
  const int h = bid & 127;

  const int t = threadIdx.x;

  __shared__ __align__(16) unsigned short zT[128 * 72];
  __shared__ __align__(16) unsigned short wt[64 * 72];
  __shared__ float ks[576];
  __shared__ float atts[64];
  __shared__ float bcs[64];

  // ---- stage wt (bf16, swizzled), ks, atts, bcs ----
  {
    const int o = t >> 2;
    const int c0 = (t & 3) * 16;
    const float* wp = W_conv + o * 64 + c0;
    float4 a0 = *(const float4*)(wp);
    float4 a1 = *(const float4*)(wp + 4);
    float4 a2 = *(const float4*)(wp + 8);
    float4 a3 = *(const float4*)(wp + 12);
    const int sw = ((o >> 2) ^ (o >> 5)) & 7;
    short8 p0, p1;
    p0[0] = f2bf(a0.x); p0[1] = f2bf(a0.y); p0[2] = f2bf(a0.z); p0[3] = f2bf(a0.w);
    p0[4] = f2bf(a1.x); p0[5] = f2bf(a1.y); p0[6] = f2bf(a1.z); p0[7] = f2bf(a1.w);
    p1[0] = f2bf(a2.x); p1[1] = f2bf(a2.y); p1[2] = f2bf(a2.z); p1[3] = f2bf(a2.w);
    p1[4] = f2bf(a3.x); p1[5] = f2bf(a3.y); p1[6] = f2bf(a3.z); p1[7] = f2bf(a3.w);
    const int kc0 = ((c0 >> 3) + 0) ^ sw;
    const int kc1 = ((c0 >> 3) + 1) ^ sw;
    *(short8*)&wt[o * 72 + kc0 * 8] = p0;
    *(short8*)&wt[o * 72 + kc1 * 8] = p1;
  }
  for (int i = t; i < 576; i += 256) ks[i] = kern_ws[b * 576 + i];
  if (t < 64) { atts[t] = att_ws[b * 64 + t]; bcs[t] = b_conv[t]; }
  __syncthreads();

  const size_t base_b = (size_t)b * 64 * 128 * 128;
  const int lane = t & 63, wave = t >> 6;
  const int cq = t >> 5;        // 0..7: channel quad group
  const int gg = t & 31;        // w-group, w0 = gg*4
  const int w0 = gg * 4;
  const int swz = (gg ^ (gg >> 3)) & 7;
  const float4 zf4 = {0.f, 0.f, 0.f, 0.f};

  const bool hgt0 = (h > 0), hlt = (h < 127);
  const float* fbase = feat + base_b + (size_t)h * 128 + w0;

  // ---- Phase 1: dw3x3 + lrelu -> zT (bf16, b64 writes) ----
  #pragma unroll
  for (int it = 0; it < 2; ++it) {
    const int c0 = cq * 4 + it * 32;
    float4 top[4], mid[4], bot[4];
    #pragma unroll
    for (int j = 0; j < 4; ++j) {
      const float* p = fbase + (size_t)(c0 + j) * 16384;
      mid[j] = *(const float4*)p;
      top[j] = hgt0 ? *(const float4*)(p - 128) : zf4;
      bot[j] = hlt  ? *(const float4*)(p + 128) : zf4;
    }
    unsigned short sres[4][4];
    #pragma unroll
    for (int j = 0; j < 4; ++j) {
      const float* kv = &ks[(c0 + j) * 9];
      const float k0 = kv[0], k1 = kv[1], k2 = kv[2];
      const float k3 = kv[3], k4 = kv[4], k5 = kv[5];
      const float k6 = kv[6], k7 = kv[7], k8 = kv[8];
      float a0 = 0.f, a1 = 0.f, a2 = 0.f, a3 = 0.f;
      {
        float4 m = top[j];
        float lf = __shfl(m.w, lane - 1, 64); if (gg == 0)  lf = 0.f;
        float rt = __shfl(m.x, lane + 1, 64); if (gg == 31) rt = 0.f;
        a0 += k0 * lf  + k1 * m.x + k2 * m.y;
        a1 += k0 * m.x + k1 * m.y + k2 * m.z;
        a2 += k0 * m.y + k1 * m.z + k2 * m.w;
        a3 += k0 * m.z + k1 * m.w + k2 * rt;
      }
      {
        float4 m = mid[j];
        float lf = __shfl(m.w, lane - 1, 64); if (gg == 0)  lf = 0.f;
        float rt = __shfl(m.x, lane + 1, 64); if (gg == 31) rt = 0.f;
        a0 += k3 * lf  + k4 * m.x + k5 * m.y;
        a1 += k3 * m.x + k4 * m.y + k5 * m.z;
        a2 += k3 * m.y + k4 * m.z + k5 * m.w;
        a3 += k3 * m.z + k4 * m.w + k5 * rt;
      }
      {
        float4 m = bot[j];
        float lf = __shfl(m.w, lane - 1, 64); if (gg == 0)  lf = 0.f;
        float rt = __shfl(m.x, lane + 1, 64); if (gg == 31) rt = 0.f;
        a0 += k6 * lf  + k7 * m.x + k8 * m.y;
        a1 += k6 * m.x + k7 * m.y + k8 * m.z;
        a2 += k6 * m.y + k7 * m.z + k8 * m.w;
        a3 += k6 * m.z + k7 * m.w + k8 * rt;
      }
      sres[j][0] = f2bf(lrelu(a0));
      sres[j][1] = f2bf(lrelu(a1));
      sres[j][2] = f2bf(lrelu(a2));
      sres[j][3] = f2bf(lrelu(a3));
    }
    const int chunk = (cq >> 1) + it * 4;
    const int kcs = ((chunk ^ swz) * 8) + (cq & 1) * 4;
    #pragma unroll
    for (int i = 0; i < 4; ++i) {
      short4v sv;
      sv[0] = (short)sres[0][i]; sv[1] = (short)sres[1][i];
      sv[2] = (short)sres[2][i]; sv[3] = (short)sres[3][i];
      *(short4v*)&zT[(w0 + i) * 72 + kcs] = sv;
    }
  }
  __syncthreads();

  // ---- Phase 2: 1x1 conv via MFMA (A=z -> D rows are w) + epilogue ----
  {
    const int r = lane & 15, q = lane >> 4;

    short8 az[2][2];
    #pragma unroll
    for (int wm2 = 0; wm2 < 2; ++wm2) {
      const int w = (wave * 2 + wm2) * 16 + r;
      const int sz = ((w >> 2) ^ (w >> 5)) & 7;
      #pragma unroll
      for (int ksp = 0; ksp < 2; ++ksp) {
        const int kc = (ksp * 4 + q) ^ sz;
        az[wm2][ksp] = *(const short8*)&zT[w * 72 + kc * 8];
      }
    }
    short8 bw[4][2];
    #pragma unroll
    for (int nt = 0; nt < 4; ++nt) {
      const int o = nt * 16 + r;
      const int so = ((o >> 2) ^ (o >> 5)) & 7;
      #pragma unroll
      for (int ksp = 0; ksp < 2; ++ksp) {
        const int kc = (ksp * 4 + q) ^ so;
        bw[nt][ksp] = *(const short8*)&wt[o * 72 + kc * 8];
      }
    }

    floatx4 acc[2][4];
    #pragma unroll
    for (int wm2 = 0; wm2 < 2; ++wm2)
      #pragma unroll
      for (int nt = 0; nt < 4; ++nt) acc[wm2][nt] = (floatx4){0.f, 0.f, 0.f, 0.f};

    #pragma unroll
    for (int wm2 = 0; wm2 < 2; ++wm2)
      #pragma unroll
      for (int nt = 0; nt < 4; ++nt)
        #pragma unroll
        for (int ksp = 0; ksp < 2; ++ksp)
          acc[wm2][nt] = __builtin_amdgcn_mfma_f32_16x16x32_bf16(
              az[wm2][ksp], bw[nt][ksp], acc[wm2][nt], 0, 0, 0);

    #pragma unroll
    for (int wm2 = 0; wm2 < 2; ++wm2) {
      const int wb = (wave * 2 + wm2) * 16 + q * 4;
      #pragma unroll
      for (int nt = 0; nt < 4; ++nt) {
        const int o = nt * 16 + r;
        const size_t off = base_b + (size_t)o * 16384 + (size_t)h * 128 + wb;
        float4 fv = *(const float4*)(feat + off);
        const float at = atts[o], bo = bcs[o];
        floatx4 a = acc[wm2][nt];
        float4 ov;
        ov.x = a[0] + bo + at * fv.x;
        ov.y = a[1] + bo + at * fv.y;
        ov.z = a[2] + bo + at * fv.z;
        ov.w = a[3] + bo + at * fv.w;
        *(float4*)(out + off) = ov;
      }
    }
  }
}

extern "C" void kernel_launch(void* const* d_in, const int* in_sizes, int n_in,
                              void* d_out, int out_size, void* d_ws, size_t ws_size,
                              hipStream_t stream) {
  const float* feat   = (const float*)d_in[0];
  const float* deg    = (const float*)d_in[1];
  const float* W_size = (const float*)d_in[2];
  const float* W_k1   = (const float*)d_in[3];
  const float* W_k2   = (const float*)d_in[4];
  const float* W_conv = (const float*)d_in[5];
  const float* b_conv = (const float*)d_in[6];
  const float* W_ac   = (const float*)d_in[7];
  const float* W_du1  = (const float*)d_in[8];
  const float* W_du2  = (const float*)d_in[9];
  float* out = (float*)d_out;

  float* kern_ws = (float*)d_ws;            // 16*576
  float* att_ws  = kern_ws + 16 * 576;      // 16*64

  prep_kernel<<<16, 256, 0, stream>>>(deg, W_size, W_k1, W_k2, W_ac, W_du1,
                                      W_du2, kern_ws, att_ws);
  fused_kernel<<<2048, 256, 0, stream>>>(feat, W_conv, b_conv, kern_ws, att_ws,
                                         out);
}